// Round 7
// baseline (870.824 us; speedup 1.0000x reference)
//
#include <hip/hip_runtime.h>
#include <math.h>
#include <limits.h>

#define DF 512
#define DH 64
#define DL 16
#define NC 10
#define NF 10
#define KPROP 10

#define BSH 7                  // bucket shift: 128 nodes per bucket
#define BW  (1 << BSH)
#define MAXB 1024
#define TILE 16384

__device__ __forceinline__ float softplus_(float x){
  return fmaxf(x, 0.0f) + log1pf(expf(-fabsf(x)));
}

// -------- GEMM1 fused with z-projection: z = relu(x@W1+b1) @ W2 + b2 --------
// 128x64 tile, 128 threads, 8x8 microtile, BK=16 -> 2 FLOP per LDS byte.
#define BM 128
#define BKK 16
__global__ __launch_bounds__(128) void k_gemm1z(const float* __restrict__ x,
    const float* __restrict__ W1, const float* __restrict__ b1,
    const float* __restrict__ W2, const float* __restrict__ b2,
    float* __restrict__ z, int N)
{
  __shared__ float At[BKK][132];   // x tile transposed [kk][row], stride 132
  __shared__ float Bs[BKK][68];    // W1 tile [kk][col], stride 68
  __shared__ float W2s[DH][17];    // stride 17 -> conflict-free scalar reads
  __shared__ float b2s[DL];
  const int tid = threadIdx.x;
  for (int i = tid; i < DH*DL; i += 128){ W2s[i>>4][i&15] = W2[i]; }
  if (tid < DL) b2s[tid] = b2[tid];
  const int tx = tid & 7, ty = tid >> 3;        // 8 col-groups x 16 row-groups
  const int row0 = blockIdx.x * BM;
  const int myrow = row0 + tid;
  const bool rowok = (myrow < N);
  const float* xr = x + (size_t)(rowok ? myrow : 0) * DF;

  float acc[8][8] = {};
  for (int k0 = 0; k0 < DF; k0 += BKK){
    // stage x tile: thread owns row `tid`, loads 4x float4 along k.
    // At store banks: (132*(kk)+r)%32 with r=lane-consecutive -> 2-way (free).
    #pragma unroll
    for (int j = 0; j < 4; ++j){
      float4 va = make_float4(0.f,0.f,0.f,0.f);
      if (rowok) va = *(const float4*)&xr[k0 + j*4];
      At[j*4+0][tid] = va.x; At[j*4+1][tid] = va.y;
      At[j*4+2][tid] = va.z; At[j*4+3][tid] = va.w;
    }
    // stage W1 tile: 16x64 floats = 256 float4, 2 per thread
    #pragma unroll
    for (int j = 0; j < 2; ++j){
      int idx = tid + j*128;
      int kk = idx >> 4, c4 = (idx & 15) << 2;
      float4 vb = *(const float4*)&W1[(size_t)(k0+kk)*DH + c4];
      *(float4*)&Bs[kk][c4] = vb;
    }
    __syncthreads();
    #pragma unroll
    for (int kk = 0; kk < BKK; ++kk){
      float4 a0 = *(const float4*)&At[kk][ty*8];
      float4 a1 = *(const float4*)&At[kk][ty*8+4];
      float4 b0 = *(const float4*)&Bs[kk][tx*8];
      float4 b1v= *(const float4*)&Bs[kk][tx*8+4];
      float a8[8] = {a0.x,a0.y,a0.z,a0.w,a1.x,a1.y,a1.z,a1.w};
      float b8[8] = {b0.x,b0.y,b0.z,b0.w,b1v.x,b1v.y,b1v.z,b1v.w};
      #pragma unroll
      for (int i=0;i<8;++i)
        #pragma unroll
        for (int j=0;j<8;++j) acc[i][j] = fmaf(a8[i], b8[j], acc[i][j]);
    }
    __syncthreads();
  }

  // epilogue: relu + bias in registers, then z = h @ W2 via per-thread
  // partials over this thread's 8 h-columns + 8-lane shuffle reduction.
  float4 bv0 = *(const float4*)&b1[tx*8];
  float4 bv1 = *(const float4*)&b1[tx*8+4];
  float bb[8] = {bv0.x,bv0.y,bv0.z,bv0.w,bv1.x,bv1.y,bv1.z,bv1.w};
  #pragma unroll
  for (int i=0;i<8;++i)
    #pragma unroll
    for (int j=0;j<8;++j) acc[i][j] = fmaxf(acc[i][j] + bb[j], 0.0f);

  #pragma unroll
  for (int b = 0; b < 4; ++b){              // 4 batches of 2 rows
    float zp[2][16];
    #pragma unroll
    for (int rr=0; rr<2; ++rr)
      #pragma unroll
      for (int c=0; c<16; ++c) zp[rr][c] = 0.f;
    #pragma unroll
    for (int j=0; j<8; ++j){
      int c = tx*8 + j;
      float w2r[16];
      #pragma unroll
      for (int zc=0; zc<16; ++zc) w2r[zc] = W2s[c][zc];
      float h0 = acc[b*2+0][j], h1 = acc[b*2+1][j];
      #pragma unroll
      for (int zc=0; zc<16; ++zc){
        zp[0][zc] = fmaf(h0, w2r[zc], zp[0][zc]);
        zp[1][zc] = fmaf(h1, w2r[zc], zp[1][zc]);
      }
    }
    #pragma unroll
    for (int rr=0; rr<2; ++rr){
      #pragma unroll
      for (int zc=0; zc<16; ++zc){
        float v = zp[rr][zc];
        v += __shfl_xor(v, 1, 8);
        v += __shfl_xor(v, 2, 8);
        v += __shfl_xor(v, 4, 8);
        zp[rr][zc] = v + b2s[zc];
      }
      int grow = row0 + ty*8 + b*2 + rr;
      if (tx < 4 && grow < N){
        float4 o;
        if      (tx == 0) o = make_float4(zp[rr][0], zp[rr][1], zp[rr][2], zp[rr][3]);
        else if (tx == 1) o = make_float4(zp[rr][4], zp[rr][5], zp[rr][6], zp[rr][7]);
        else if (tx == 2) o = make_float4(zp[rr][8], zp[rr][9], zp[rr][10],zp[rr][11]);
        else              o = make_float4(zp[rr][12],zp[rr][13],zp[rr][14],zp[rr][15]);
        ((float4*)z)[(size_t)grow*4 + tx] = o;
      }
    }
  }
}

// -------- radial flows: one thread per (node, class) --------
// emits x0 (=beta_ft), c0 = dinv*x0, y0 = 0.1*dinv*x0
__global__ __launch_bounds__(256) void k_flow2(const float* __restrict__ z,
    const float* __restrict__ pc, const float* __restrict__ z0g,
    const float* __restrict__ apg, const float* __restrict__ fbg,
    const float* __restrict__ dinv,
    float* __restrict__ x0, float* __restrict__ c0, float* __restrict__ y0, int N)
{
  __shared__ float z0s[NF][NC][DL];
  __shared__ float alps[NF][NC];
  __shared__ float bhs[NF][NC];
  __shared__ float lpc[NC];
  int tid = threadIdx.x;
  for (int i = tid; i < NF*NC*DL; i += 256)
    z0s[(i>>4)/NC][(i>>4)%NC][i&15] = z0g[i];
  if (tid < NF*NC){
    int l = tid/NC, c = tid%NC;
    float al = softplus_(apg[tid]);
    alps[l][c] = al;
    bhs[l][c]  = -al + softplus_(fbg[tid]);
  }
  if (tid < NC) lpc[tid] = __logf(pc[tid]);
  __syncthreads();

  int idx = blockIdx.x*256 + tid;
  int n = idx >> 4, c = idx & 15;
  if (n >= N) return;
  float dn = dinv[n];
  if (c >= NC){ x0[idx] = 0.f; c0[idx] = 0.f; y0[idx] = 0.f; return; }

  float zz[DL];
  const float4* z4 = (const float4*)z;
  #pragma unroll
  for (int q=0; q<4; ++q){
    float4 v = z4[(size_t)n*4 + q];
    zz[q*4+0]=v.x; zz[q*4+1]=v.y; zz[q*4+2]=v.z; zz[q*4+3]=v.w;
  }
  const float NEGHALFD_LOG2PI = -14.703016531274762f;  // -8*log(2*pi)
  const float LOGSCALE        =  20.248193975754326f;  //  8*log(4*pi)
  float sld = 0.f;
  #pragma unroll 1
  for (int l=0; l<NF; ++l){
    float al = alps[l][c], bhat = bhs[l][c];
    float dz[DL]; float r2 = 0.f;
    #pragma unroll
    for (int d=0; d<DL; ++d){ float t = zz[d] - z0s[l][c][d]; dz[d]=t; r2 = fmaf(t,t,r2); }
    float r  = sqrtf(r2);
    float hh = 1.0f/(al + r);
    float bh = bhat*hh;
    #pragma unroll
    for (int d=0; d<DL; ++d) zz[d] = fmaf(bh, dz[d], zz[d]);
    sld += 15.0f*__logf(1.0f + bh) + __logf(1.0f + bh - bhat*r*hh*hh);
  }
  float q2 = 0.f;
  #pragma unroll
  for (int d=0; d<DL; ++d) q2 = fmaf(zz[d], zz[d], q2);
  float v = -0.5f*q2 + NEGHALFD_LOG2PI + sld + lpc[c] + LOGSCALE;
  v = fminf(fmaxf(v, -30.f), 30.f);
  float xv = __expf(v);
  x0[idx] = xv;
  c0[idx] = dn*xv;
  y0[idx] = 0.1f*dn*xv;
}

// ---------------- bucketed CSR construction ----------------
__global__ __launch_bounds__(256) void k_bhist(const int* __restrict__ dst,
    int* __restrict__ bCnt, int E, int B)
{
  __shared__ int hh[MAXB];
  int tid = threadIdx.x;
  for (int b = tid; b < B; b += 256) hh[b] = 0;
  __syncthreads();
  for (int i = blockIdx.x*256 + tid; i < E; i += gridDim.x*256)
    atomicAdd(&hh[dst[i] >> BSH], 1);
  __syncthreads();
  for (int b = tid; b < B; b += 256) if (hh[b]) atomicAdd(&bCnt[b], hh[b]);
}

__global__ void k_bscan(const int* __restrict__ bCnt, int* __restrict__ bOff, int B){
  if (blockIdx.x==0 && threadIdx.x==0){
    int run = 0;
    for (int b=0;b<B;++b){ bOff[b]=run; run+=bCnt[b]; }
    bOff[B]=run;
  }
}

__global__ __launch_bounds__(256) void k_bscatter(const int* __restrict__ src,
    const int* __restrict__ dst, const int* __restrict__ bOff,
    int* __restrict__ bCur, int* __restrict__ bp, int E, int B)
{
  __shared__ int hc[MAXB];
  __shared__ int hb[MAXB];
  int tid = threadIdx.x;
  int base = blockIdx.x * TILE;
  int lim  = base + TILE; if (lim > E) lim = E;
  for (int b = tid; b < B; b += 256) hc[b] = 0;
  __syncthreads();
  for (int i = base + tid; i < lim; i += 256)
    atomicAdd(&hc[dst[i] >> BSH], 1);
  __syncthreads();
  for (int b = tid; b < B; b += 256){
    int c = hc[b];
    hb[b] = c ? atomicAdd(&bCur[b], c) : 0;
    hc[b] = 0;
  }
  __syncthreads();
  for (int i = base + tid; i < lim; i += 256){
    int d = dst[i];
    int b = d >> BSH;
    int pos = bOff[b] + hb[b] + atomicAdd(&hc[b], 1);
    bp[pos] = (src[i] << BSH) | (d & (BW-1));
  }
}

// per-bucket in-degree count (+1 self loop) fused with dinv/dinv2
__global__ __launch_bounds__(256) void k_bdeg(const int* __restrict__ bp,
    const int* __restrict__ bOff, int* __restrict__ deg,
    float* __restrict__ dinv, float* __restrict__ dinv2, int N)
{
  __shared__ int cur[BW];
  int tid = threadIdx.x;
  int b = blockIdx.x;
  if (tid < BW) cur[tid] = 0;
  __syncthreads();
  int s = bOff[b], e = bOff[b+1];
  for (int i = s + tid; i < e; i += 256)
    atomicAdd(&cur[bp[i] & (BW-1)], 1);
  __syncthreads();
  int node = (b << BSH) + tid;
  if (tid < BW && node < N){
    int d = cur[tid] + 1;                 // +1 self loop
    deg[node] = d;
    float dv = 1.0f / sqrtf((float)d);
    dinv[node]  = dv;
    dinv2[node] = dv*dv;
  }
}

__global__ __launch_bounds__(256) void k_scan_part(const int* __restrict__ deg,
    int* __restrict__ part, int N){
  __shared__ int sd[256];
  int base = blockIdx.x*1024;
  int tid = threadIdx.x;
  int s = 0;
  #pragma unroll
  for (int i=0;i<4;++i){ int idx = base + tid*4 + i; if (idx < N) s += deg[idx]; }
  sd[tid] = s; __syncthreads();
  for (int ofs=128; ofs>0; ofs>>=1){ if (tid<ofs) sd[tid]+=sd[tid+ofs]; __syncthreads(); }
  if (tid==0) part[blockIdx.x] = sd[0];
}

__global__ void k_scan_top(int* part, int nb){
  if (blockIdx.x==0 && threadIdx.x==0){
    int run = 0;
    for (int i=0;i<nb;++i){ int v = part[i]; part[i] = run; run += v; }
  }
}

__global__ __launch_bounds__(256) void k_scan_final(const int* __restrict__ deg,
    const int* __restrict__ part, int* __restrict__ off, int N, int E)
{
  __shared__ int sc[256];
  int base = blockIdx.x*1024;
  int tid = threadIdx.x;
  int v[4]; int s = 0;
  #pragma unroll
  for (int i=0;i<4;++i){ int idx = base + tid*4 + i; v[i] = (idx<N)?deg[idx]:0; s += v[i]; }
  sc[tid] = s; __syncthreads();
  for (int ofs=1; ofs<256; ofs<<=1){
    int t = (tid>=ofs) ? sc[tid-ofs] : 0;
    __syncthreads();
    sc[tid] += t;
    __syncthreads();
  }
  int ex = sc[tid] - s + part[blockIdx.x];
  #pragma unroll
  for (int i=0;i<4;++i){
    int idx = base + tid*4 + i;
    if (idx < N){
      off[idx] = ex;
      if (idx == N-1) off[N] = ex + v[i];
      ex += v[i];
    }
  }
}

// place self edge (slot 0) + src ints at CSR positions
__global__ __launch_bounds__(256) void k_place(const int* __restrict__ bp,
    const int* __restrict__ bOff, const int* __restrict__ off,
    int* __restrict__ csr, int N)
{
  __shared__ int cur[BW];
  int tid = threadIdx.x;
  int b = blockIdx.x;
  int node0 = b << BSH;
  if (tid < BW){
    cur[tid] = 1;                                 // slot 0 reserved for self
    int node = node0 + tid;
    if (node < N) csr[off[node]] = node;
  }
  __syncthreads();
  int s = bOff[b], e = bOff[b+1];
  for (int i = s + tid; i < e; i += 256){
    int v  = bp[i];
    int dl = v & (BW-1);
    int sn = v >> BSH;
    int d  = node0 + dl;
    int p  = off[d] + atomicAdd(&cur[dl], 1);
    csr[p] = sn;
  }
}

// ---- canonicalize segment order (stable value-rank via shuffles) ----
__global__ __launch_bounds__(256) void k_rank(int* __restrict__ csr,
    const int* __restrict__ off, int N)
{
  int wid  = (blockIdx.x*256 + threadIdx.x) >> 6;
  int lane = threadIdx.x & 63;
  if (wid >= N) return;
  int s = off[wid], e = off[wid+1];
  int d = e - s;
  if (d <= 1) return;
  if (d <= 64){
    int v = (lane < d) ? csr[s+lane] : INT_MAX;
    int rank = 0;
    for (int j = 0; j < d; ++j){
      int bv = __shfl(v, j);
      rank += (bv < v) || (bv == v && j < lane);
    }
    if (lane < d) csr[s+rank] = v;
  } else if (d <= 256){
    int v0 = (lane      < d) ? csr[s+lane      ] : INT_MAX;
    int v1 = (lane+64   < d) ? csr[s+lane+64   ] : INT_MAX;
    int v2 = (lane+128  < d) ? csr[s+lane+128  ] : INT_MAX;
    int v3 = (lane+192  < d) ? csr[s+lane+192  ] : INT_MAX;
    int r0=0,r1=0,r2=0,r3=0;
    for (int j = 0; j < d; ++j){
      int slot = j >> 6, jl = j & 63;
      int bv = (slot==0) ? __shfl(v0,jl) : (slot==1) ? __shfl(v1,jl)
             : (slot==2) ? __shfl(v2,jl) : __shfl(v3,jl);
      r0 += (bv < v0) || (bv == v0 && j < lane);
      r1 += (bv < v1) || (bv == v1 && j < lane+64);
      r2 += (bv < v2) || (bv == v2 && j < lane+128);
      r3 += (bv < v3) || (bv == v3 && j < lane+192);
    }
    if (lane      < d) csr[s+r0]=v0;
    if (lane+64   < d) csr[s+r1]=v1;
    if (lane+128  < d) csr[s+r2]=v2;
    if (lane+192  < d) csr[s+r3]=v3;
  } else {
    if (lane == 0){
      for (int i = s+1; i < e; ++i){
        int key = csr[i]; int j = i-1;
        while (j >= s && csr[j] > key){ csr[j+1] = csr[j]; --j; }
        csr[j+1] = key;
      }
    }
  }
}

// ---- APPNP c-space iteration: c' = 0.9*dinv2*sum(c[src]) + y0 ----
__global__ __launch_bounds__(256) void k_prop(const float* __restrict__ cin,
    const float* __restrict__ y0, const float* __restrict__ dinv2,
    float* __restrict__ cout,
    const int* __restrict__ csr, const int* __restrict__ off, int N)
{
  int t = blockIdx.x*256 + threadIdx.x;
  int n = t >> 2, q = t & 3;
  if (n >= N) return;
  const float4* c4 = (const float4*)cin;
  float4 a0 = make_float4(0.f,0.f,0.f,0.f);
  float4 a1 = make_float4(0.f,0.f,0.f,0.f);
  float4 a2 = make_float4(0.f,0.f,0.f,0.f);
  float4 a3 = make_float4(0.f,0.f,0.f,0.f);
  int s = off[n], e = off[n+1];
  int i = s;
  for (; i+8 <= e; i += 8){
    int s0 = csr[i],   s1 = csr[i+1], s2 = csr[i+2], s3 = csr[i+3];
    int s4 = csr[i+4], s5 = csr[i+5], s6 = csr[i+6], s7 = csr[i+7];
    float4 v0 = c4[(size_t)s0*4 + q];
    float4 v1 = c4[(size_t)s1*4 + q];
    float4 v2 = c4[(size_t)s2*4 + q];
    float4 v3 = c4[(size_t)s3*4 + q];
    float4 v4 = c4[(size_t)s4*4 + q];
    float4 v5 = c4[(size_t)s5*4 + q];
    float4 v6 = c4[(size_t)s6*4 + q];
    float4 v7 = c4[(size_t)s7*4 + q];
    a0.x += v0.x; a0.y += v0.y; a0.z += v0.z; a0.w += v0.w;
    a1.x += v1.x; a1.y += v1.y; a1.z += v1.z; a1.w += v1.w;
    a2.x += v2.x; a2.y += v2.y; a2.z += v2.z; a2.w += v2.w;
    a3.x += v3.x; a3.y += v3.y; a3.z += v3.z; a3.w += v3.w;
    a0.x += v4.x; a0.y += v4.y; a0.z += v4.z; a0.w += v4.w;
    a1.x += v5.x; a1.y += v5.y; a1.z += v5.z; a1.w += v5.w;
    a2.x += v6.x; a2.y += v6.y; a2.z += v6.z; a2.w += v6.w;
    a3.x += v7.x; a3.y += v7.y; a3.z += v7.z; a3.w += v7.w;
  }
  for (; i+4 <= e; i += 4){
    int s0 = csr[i], s1 = csr[i+1], s2 = csr[i+2], s3 = csr[i+3];
    float4 v0 = c4[(size_t)s0*4 + q];
    float4 v1 = c4[(size_t)s1*4 + q];
    float4 v2 = c4[(size_t)s2*4 + q];
    float4 v3 = c4[(size_t)s3*4 + q];
    a0.x += v0.x; a0.y += v0.y; a0.z += v0.z; a0.w += v0.w;
    a1.x += v1.x; a1.y += v1.y; a1.z += v1.z; a1.w += v1.w;
    a2.x += v2.x; a2.y += v2.y; a2.z += v2.z; a2.w += v2.w;
    a3.x += v3.x; a3.y += v3.y; a3.z += v3.z; a3.w += v3.w;
  }
  for (; i < e; ++i){
    float4 v0 = c4[(size_t)csr[i]*4 + q];
    a0.x += v0.x; a0.y += v0.y; a0.z += v0.z; a0.w += v0.w;
  }
  float w9 = 0.9f * dinv2[n];
  float4 yv = ((const float4*)y0)[(size_t)n*4 + q];
  float4 o;
  o.x = fmaf(w9, (a0.x+a1.x)+(a2.x+a3.x), yv.x);
  o.y = fmaf(w9, (a0.y+a1.y)+(a2.y+a3.y), yv.y);
  o.z = fmaf(w9, (a0.z+a1.z)+(a2.z+a3.z), yv.z);
  o.w = fmaf(w9, (a0.w+a1.w)+(a2.w+a3.w), yv.w);
  ((float4*)cout)[(size_t)n*4 + q] = o;
}

// ---- last iteration fused with alpha/soft/argmax: beta = 0.9*dinv*sum + 0.1*x0 ----
__global__ __launch_bounds__(256) void k_prop_final(const float* __restrict__ cin,
    const float* __restrict__ x0, const float* __restrict__ dinv,
    const int* __restrict__ csr, const int* __restrict__ off,
    float* __restrict__ out, int N)
{
  int t = blockIdx.x*256 + threadIdx.x;
  int n = t >> 2, q = t & 3;
  if (n >= N) return;
  const float4* c4 = (const float4*)cin;
  float4 a0 = make_float4(0.f,0.f,0.f,0.f);
  float4 a1 = make_float4(0.f,0.f,0.f,0.f);
  float4 a2 = make_float4(0.f,0.f,0.f,0.f);
  float4 a3 = make_float4(0.f,0.f,0.f,0.f);
  int s = off[n], e = off[n+1];
  int i = s;
  for (; i+4 <= e; i += 4){
    int s0 = csr[i], s1 = csr[i+1], s2 = csr[i+2], s3 = csr[i+3];
    float4 v0 = c4[(size_t)s0*4 + q];
    float4 v1 = c4[(size_t)s1*4 + q];
    float4 v2 = c4[(size_t)s2*4 + q];
    float4 v3 = c4[(size_t)s3*4 + q];
    a0.x += v0.x; a0.y += v0.y; a0.z += v0.z; a0.w += v0.w;
    a1.x += v1.x; a1.y += v1.y; a1.z += v1.z; a1.w += v1.w;
    a2.x += v2.x; a2.y += v2.y; a2.z += v2.z; a2.w += v2.w;
    a3.x += v3.x; a3.y += v3.y; a3.z += v3.z; a3.w += v3.w;
  }
  for (; i < e; ++i){
    float4 v0 = c4[(size_t)csr[i]*4 + q];
    a0.x += v0.x; a0.y += v0.y; a0.z += v0.z; a0.w += v0.w;
  }
  float w9 = 0.9f * dinv[n];
  float4 xv = ((const float4*)x0)[(size_t)n*4 + q];
  float4 al;
  al.x = fmaf(w9, (a0.x+a1.x)+(a2.x+a3.x), fmaf(0.1f, xv.x, 1.f));
  al.y = fmaf(w9, (a0.y+a1.y)+(a2.y+a3.y), fmaf(0.1f, xv.y, 1.f));
  al.z = fmaf(w9, (a0.z+a1.z)+(a2.z+a3.z), fmaf(0.1f, xv.z, 1.f));
  al.w = fmaf(w9, (a0.w+a1.w)+(a2.w+a3.w), fmaf(0.1f, xv.w, 1.f));

  float sv = 0.f;
  if (q < 2)       sv = al.x + al.y + al.z + al.w;
  else if (q == 2) sv = al.x + al.y;
  sv += __shfl_xor(sv, 1, 4);
  sv += __shfl_xor(sv, 2, 4);

  float bv = -1e30f; int bi = 999;
  int cb = q*4;
  int nvalid = (q < 2) ? 4 : (q == 2 ? 2 : 0);
  float av[4] = {al.x, al.y, al.z, al.w};
  for (int j = 0; j < nvalid; ++j){
    if (av[j] > bv){ bv = av[j]; bi = cb + j; }
  }
  #pragma unroll
  for (int o = 1; o <= 2; o <<= 1){
    float vo = __shfl_xor(bv, o, 4);
    int  io  = __shfl_xor(bi, o, 4);
    if (vo > bv || (vo == bv && io < bi)){ bv = vo; bi = io; }
  }

  float inv = 1.0f / sv;
  size_t sb = (size_t)N + (size_t)n*NC;
  for (int j = 0; j < nvalid; ++j) out[sb + cb + j] = av[j] * inv;
  if (q == 0) out[n] = (float)bi;
}

extern "C" void kernel_launch(void* const* d_in, const int* in_sizes, int n_in,
                              void* d_out, int out_size, void* d_ws, size_t ws_size,
                              hipStream_t stream)
{
  const float* x  = (const float*)d_in[0];
  const int*   ei = (const int*)  d_in[1];
  const float* pc = (const float*)d_in[2];
  const float* W1 = (const float*)d_in[3];
  const float* b1 = (const float*)d_in[4];
  const float* W2 = (const float*)d_in[5];
  const float* b2 = (const float*)d_in[6];
  const float* z0 = (const float*)d_in[7];
  const float* ap = (const float*)d_in[8];
  const float* fb = (const float*)d_in[9];
  float* out = (float*)d_out;

  const int N = in_sizes[0] / DF;
  const int E = in_sizes[1] / 2;
  const int* src = ei;
  const int* dst = ei + E;
  const int B = (N + BW - 1) >> BSH;

  // Workspace. region0 holds bp (E ints) during CSR build, then z (N*16 f32)
  // for the encoder (bp is dead after k_place).
  char* ws = (char*)d_ws;
  size_t o = 0;
  size_t region0 = (size_t)E*sizeof(int);
  if ((size_t)N*DL*sizeof(float) > region0) region0 = (size_t)N*DL*sizeof(float);
  int*   bp   = (int*)  (ws + o);
  float* z    = (float*)(ws + o);
  o += region0;
  int*   csr  = (int*)  (ws + o); o += (size_t)(E+N)*sizeof(int);   // +N self edges
  float* x0   = (float*)(ws + o); o += (size_t)N*DL*sizeof(float);
  float* c0   = (float*)(ws + o); o += (size_t)N*DL*sizeof(float);
  float* y0   = (float*)(ws + o); o += (size_t)N*DL*sizeof(float);
  float* cA   = (float*)(ws + o); o += (size_t)N*DL*sizeof(float);
  float* cB   = (float*)(ws + o); o += (size_t)N*DL*sizeof(float);
  int*   deg  = (int*)  (ws + o); o += (size_t)N*sizeof(int);
  float* dinv = (float*)(ws + o); o += (size_t)N*sizeof(float);
  float* dinv2= (float*)(ws + o); o += (size_t)N*sizeof(float);
  int*   offs = (int*)  (ws + o); o += (size_t)(N+2)*sizeof(int);
  int*   part = (int*)  (ws + o); o += 4096;
  int*   bCnt = (int*)  (ws + o); o += MAXB*sizeof(int);
  int*   bOff = (int*)  (ws + o); o += (MAXB+1)*sizeof(int);
  int*   bCur = (int*)  (ws + o); o += MAXB*sizeof(int);

  const int TB = 256;
  int nb  = (N + 1023) / 1024;

  // Phase 1: bucketed CSR build (bp lives in region0)
  hipMemsetAsync(bCnt, 0, MAXB*sizeof(int), stream);
  hipMemsetAsync(bCur, 0, MAXB*sizeof(int), stream);
  k_bhist<<<512, TB, 0, stream>>>(dst, bCnt, E, B);
  k_bscan<<<1, 1, 0, stream>>>(bCnt, bOff, B);
  k_bscatter<<<(E + TILE - 1)/TILE, TB, 0, stream>>>(src, dst, bOff, bCur, bp, E, B);
  k_bdeg<<<B, TB, 0, stream>>>(bp, bOff, deg, dinv, dinv2, N);
  k_scan_part<<<nb, TB, 0, stream>>>(deg, part, N);
  k_scan_top<<<1, 1, 0, stream>>>(part, nb);
  k_scan_final<<<nb, TB, 0, stream>>>(deg, part, offs, N, E);
  k_place<<<B, TB, 0, stream>>>(bp, bOff, offs, csr, N);
  k_rank<<<(N + 3) / 4, TB, 0, stream>>>(csr, offs, N);

  // Phase 2: encoder fused with z projection (z overwrites bp), then flows
  k_gemm1z<<<(N + BM - 1) / BM, 128, 0, stream>>>(x, W1, b1, W2, b2, z, N);
  k_flow2<<<((N*DL) + TB - 1) / TB, TB, 0, stream>>>(z, pc, z0, ap, fb, dinv,
                                                     x0, c0, y0, N);

  // Phase 3: APPNP in c-space — 9 iterations + 1 fused with the epilogue
  int gP = ((N*4) + TB - 1) / TB;
  const float* cin = c0;
  for (int it = 0; it < KPROP-1; ++it){
    float* cout = (it & 1) ? cB : cA;
    k_prop<<<gP, TB, 0, stream>>>(cin, y0, dinv2, cout, csr, offs, N);
    cin = cout;
  }
  k_prop_final<<<gP, TB, 0, stream>>>(cin, x0, dinv, csr, offs, out, N);
}